// Round 1
// baseline (259.915 us; speedup 1.0000x reference)
//
#include <hip/hip_runtime.h>

#define BB   256
#define NIN  1152
#define OO   10
#define IL   8
#define OL   16
#define EPSQ 1e-7f

constexpr int GROUPS = 16;        // 16-lane groups per block, one b each
constexpr int NPER   = 32;        // n's per block
constexpr int CH     = NIN / NPER; // 36 chunks

// Computes, for each (b, n-chunk), the partial sum over n of c[b,n,o]*u_hat[b,n,o,k].
// vsum == nullptr  -> iteration 0 (b_ij = 0, c = 1/O uniform).
// vsum != nullptr  -> c = softmax_o( sum_k u_hat[b,n,o,k] * vsum[b,o,k] ).
__global__ __launch_bounds__(256) void caps_partial(
    const float* __restrict__ x,       // [B][NIN][IL]
    const float* __restrict__ w,       // [NIN][O][IL][OL]
    const float* __restrict__ vsum,    // [B][O][OL] or null
    float* __restrict__ partial)       // [B][CH][O][OL]
{
    const int t = threadIdx.x;
    const int g = t >> 4;              // group within block
    const int k = t & 15;              // lane within group = output-cap dim
    const int b = blockIdx.x * GROUPS + g;
    const int chunk = blockIdx.y;
    const int n0 = chunk * NPER;

    const bool uniform = (vsum == nullptr);
    float vs[OO];
    if (!uniform) {
        #pragma unroll
        for (int o = 0; o < OO; ++o) vs[o] = vsum[(b * OO + o) * OL + k];
    }

    float sp[OO];
    #pragma unroll
    for (int o = 0; o < OO; ++o) sp[o] = 0.f;

    for (int nn = 0; nn < NPER; ++nn) {
        const int n = n0 + nn;
        // x[b,n,0:8] — same for all 16 lanes of the group (broadcast loads)
        const float4* xp4 = reinterpret_cast<const float4*>(x + ((size_t)b * NIN + n) * IL);
        const float4 xa = xp4[0];
        const float4 xb = xp4[1];
        const float xv[IL] = {xa.x, xa.y, xa.z, xa.w, xb.x, xb.y, xb.z, xb.w};

        // u_hat[o][k] for this lane's k
        const float* wp = w + (size_t)n * OO * IL * OL + k;
        float u[OO];
        #pragma unroll
        for (int o = 0; o < OO; ++o) {
            float acc = 0.f;
            #pragma unroll
            for (int i = 0; i < IL; ++i)
                acc = fmaf(wp[(o * IL + i) * OL], xv[i], acc);
            u[o] = acc;
        }

        if (uniform) {
            #pragma unroll
            for (int o = 0; o < OO; ++o) sp[o] += u[o];
        } else {
            // b_ij[o] = sum_k u[o,k] * vs[o,k]  (16-lane reduce)
            float bij[OO];
            #pragma unroll
            for (int o = 0; o < OO; ++o) {
                float td = u[o] * vs[o];
                #pragma unroll
                for (int off = 8; off >= 1; off >>= 1)
                    td += __shfl_xor(td, off, 16);
                bij[o] = td;
            }
            // softmax over o (wave-uniform within the group)
            float m = bij[0];
            #pragma unroll
            for (int o = 1; o < OO; ++o) m = fmaxf(m, bij[o]);
            float e[OO];
            float se = 0.f;
            #pragma unroll
            for (int o = 0; o < OO; ++o) { e[o] = __expf(bij[o] - m); se += e[o]; }
            const float r = 1.f / se;
            #pragma unroll
            for (int o = 0; o < OO; ++o) sp[o] = fmaf(e[o] * r, u[o], sp[o]);
        }
    }

    const float scale = uniform ? (1.f / OO) : 1.f;
    #pragma unroll
    for (int o = 0; o < OO; ++o)
        partial[(((size_t)b * CH + chunk) * OO + o) * OL + k] = sp[o] * scale;
}

// Sums partials over chunks, adds bias, applies squash; optionally adds prevAdd
// (running v-sum for the linearized b_ij update).
__global__ __launch_bounds__(192) void caps_reduce_squash(
    const float* __restrict__ partial,  // [B][CH][O][OL]
    const float* __restrict__ bias,     // [O][OL]
    const float* __restrict__ prevAdd,  // [B][O][OL] or null
    float* __restrict__ out)            // [B][O][OL]
{
    const int t = threadIdx.x;
    if (t >= OO * OL) return;
    const int b = blockIdx.x;
    const int o = t >> 4;
    const int k = t & 15;

    float s = bias[o * OL + k];
    for (int ch = 0; ch < CH; ++ch)
        s += partial[(((size_t)b * CH + ch) * OO + o) * OL + k];

    float d = s * s;
    #pragma unroll
    for (int off = 8; off >= 1; off >>= 1)
        d += __shfl_xor(d, off, 16);

    const float f = d / ((1.f + d) * sqrtf(d + EPSQ));
    float v = f * s;
    if (prevAdd) v += prevAdd[((size_t)b * OO + o) * OL + k];
    out[((size_t)b * OO + o) * OL + k] = v;
}

extern "C" void kernel_launch(void* const* d_in, const int* in_sizes, int n_in,
                              void* d_out, int out_size, void* d_ws, size_t ws_size,
                              hipStream_t stream) {
    const float* x    = (const float*)d_in[0]; // (B, NIN, 8, 1)
    const float* w    = (const float*)d_in[1]; // (1, NIN, O, 8, 16)
    const float* bias = (const float*)d_in[2]; // (1, 1, O, 16, 1)
    float* out = (float*)d_out;                // (B, 1, O, 16, 1)

    float* partial = (float*)d_ws;                           // B*CH*O*OL
    float* v0      = partial + (size_t)BB * CH * OO * OL;    // B*O*OL
    float* vsb     = v0 + (size_t)BB * OO * OL;              // B*O*OL

    const dim3 pgrid(BB / GROUPS, CH);
    const dim3 pblk(256);

    // iter 0: uniform c, produce v0
    caps_partial<<<pgrid, pblk, 0, stream>>>(x, w, nullptr, partial);
    caps_reduce_squash<<<BB, 192, 0, stream>>>(partial, bias, nullptr, v0);
    // iter 1: c = softmax(u.v0), produce vsb = v0 + v1
    caps_partial<<<pgrid, pblk, 0, stream>>>(x, w, v0, partial);
    caps_reduce_squash<<<BB, 192, 0, stream>>>(partial, bias, v0, vsb);
    // iter 2: c = softmax(u.(v0+v1)), produce final v -> d_out
    caps_partial<<<pgrid, pblk, 0, stream>>>(x, w, vsb, partial);
    caps_reduce_squash<<<BB, 192, 0, stream>>>(partial, bias, nullptr, out);
}